// Round 2
// baseline (2462.786 us; speedup 1.0000x reference)
//
#include <hip/hip_runtime.h>
#include <hip/hip_bf16.h>
#include <cstddef>

// Problem constants
#define Bsz 8
#define Sseq 1024
#define Dm 1024
#define Hh 16
#define DH 64
#define DFF 2048
#define ROWS (Bsz*Sseq)          // 8192
#define EIGHT_M (8u*1024u*1024u) // 8388608 floats

// ---------------------------------------------------------------------------
// LayerNorm: one block per row of 1024 floats. ddof=1 variance, std+1e-6.
// ---------------------------------------------------------------------------
__global__ __launch_bounds__(256) void ln_k(const float* __restrict__ x,
                                            const float* __restrict__ gain,
                                            const float* __restrict__ beta,
                                            float* __restrict__ y)
{
    int row = blockIdx.x;
    const float* xr = x + (size_t)row * Dm;
    int tid = threadIdx.x;

    float4 v = *(const float4*)&xr[tid * 4];
    float s  = v.x + v.y + v.z + v.w;
    float sq = v.x*v.x + v.y*v.y + v.z*v.z + v.w*v.w;

    #pragma unroll
    for (int off = 32; off > 0; off >>= 1) {
        s  += __shfl_down(s,  off);
        sq += __shfl_down(sq, off);
    }
    __shared__ float ss[4], ssq[4];
    int w = tid >> 6, ln = tid & 63;
    if (ln == 0) { ss[w] = s; ssq[w] = sq; }
    __syncthreads();
    float S  = ss[0] + ss[1] + ss[2] + ss[3];
    float SQ = ssq[0] + ssq[1] + ssq[2] + ssq[3];

    float mean = S * (1.0f / 1024.0f);
    float var  = (SQ - 1024.0f * mean * mean) * (1.0f / 1023.0f);
    var = fmaxf(var, 0.0f);
    float inv = 1.0f / (sqrtf(var) + 1e-6f);

    float4 gv = *(const float4*)&gain[tid * 4];
    float4 bv = *(const float4*)&beta[tid * 4];
    float4 o;
    o.x = gv.x * inv * (v.x - mean) + bv.x;
    o.y = gv.y * inv * (v.y - mean) + bv.y;
    o.z = gv.z * inv * (v.z - mean) + bv.z;
    o.w = gv.w * inv * (v.w - mean) + bv.w;
    *(float4*)&y[(size_t)row * Dm + tid * 4] = o;
}

// ---------------------------------------------------------------------------
// Tiled fp32 GEMM, 128x128 block tile, BK=16, 256 threads, 8x8 per thread
// (split 2x2 of 4x4). Epilogue modes:
//   0: QKV   — C[head layout] = A@W + bias      (A row-major)
//   1: OPROJ — C[row major]  = A@W + bias + res (A in head layout; res = x)
//   2: FFN1  — C = relu(A@W + bias)
//   3: FFN2  — C = A@W + bias + res             (res = attn)
// ---------------------------------------------------------------------------
#define BM 128
#define BN 128
#define BK 16

template<int EPI>
__global__ __launch_bounds__(256) void gemm_k(const float* __restrict__ A,
                                              const float* __restrict__ W,
                                              const float* __restrict__ bias,
                                              float* __restrict__ C,
                                              const float* __restrict__ res,
                                              int M, int N, int K)
{
    __shared__ __align__(16) float As[BK][BM + 4];
    __shared__ __align__(16) float Bs[BK][BN + 4];

    int m0 = blockIdx.y * BM;
    int n0 = blockIdx.x * BN;
    int tid = threadIdx.x;
    int tr = tid >> 4;   // 0..15
    int tc = tid & 15;   // 0..15

    float acc[2][2][4][4] = {};

    for (int k0 = 0; k0 < K; k0 += BK) {
        // --- stage A tile (128 rows x 16 k), float4 along K, transpose to As[k][m]
        #pragma unroll
        for (int l = 0; l < 2; ++l) {
            int idx = tid + l * 256;        // 0..511
            int row = idx >> 2;             // 0..127
            int kc4 = (idx & 3) * 4;        // 0,4,8,12
            int gm = m0 + row;
            int gk = k0 + kc4;
            float4 av;
            if constexpr (EPI == 1) {
                // A element (m,k) lives at head layout ((b*16+h)*1024+s)*64+d
                int b = gm >> 10, sI = gm & 1023;
                int h = gk >> 6,  d  = gk & 63;
                av = *(const float4*)&A[(((size_t)(b * 16 + h) * 1024 + sI) << 6) + d];
            } else {
                av = *(const float4*)&A[(size_t)gm * K + gk];
            }
            As[kc4 + 0][row] = av.x;
            As[kc4 + 1][row] = av.y;
            As[kc4 + 2][row] = av.z;
            As[kc4 + 3][row] = av.w;
        }
        // --- stage B tile (16 k x 128 n), float4 along N
        #pragma unroll
        for (int l = 0; l < 2; ++l) {
            int idx = tid + l * 256;        // 0..511
            int kk = idx >> 5;              // 0..15
            int nc = (idx & 31) * 4;        // 0..124
            float4 bv = *(const float4*)&W[(size_t)(k0 + kk) * N + n0 + nc];
            *(float4*)&Bs[kk][nc] = bv;
        }
        __syncthreads();

        #pragma unroll
        for (int kk = 0; kk < BK; ++kk) {
            float a[2][4], b[2][4];
            #pragma unroll
            for (int h = 0; h < 2; ++h) {
                float4 t = *(const float4*)&As[kk][tr * 4 + h * 64];
                a[h][0] = t.x; a[h][1] = t.y; a[h][2] = t.z; a[h][3] = t.w;
                float4 u = *(const float4*)&Bs[kk][tc * 4 + h * 64];
                b[h][0] = u.x; b[h][1] = u.y; b[h][2] = u.z; b[h][3] = u.w;
            }
            #pragma unroll
            for (int h = 0; h < 2; ++h)
                #pragma unroll
                for (int i = 0; i < 4; ++i)
                    #pragma unroll
                    for (int g = 0; g < 2; ++g)
                        #pragma unroll
                        for (int j = 0; j < 4; ++j)
                            acc[h][g][i][j] = fmaf(a[h][i], b[g][j], acc[h][g][i][j]);
        }
        __syncthreads();
    }

    // --- epilogue
    #pragma unroll
    for (int h = 0; h < 2; ++h) {
        #pragma unroll
        for (int i = 0; i < 4; ++i) {
            int r = m0 + tr * 4 + h * 64 + i;
            #pragma unroll
            for (int g = 0; g < 2; ++g) {
                int c = n0 + tc * 4 + g * 64;
                float4 bv = *(const float4*)&bias[c];
                float v0 = acc[h][g][i][0] + bv.x;
                float v1 = acc[h][g][i][1] + bv.y;
                float v2 = acc[h][g][i][2] + bv.z;
                float v3 = acc[h][g][i][3] + bv.w;
                if constexpr (EPI == 0) {
                    int b = r >> 10, sI = r & 1023;
                    int hh = c >> 6, d = c & 63;
                    *(float4*)&C[((size_t)((b * 16 + hh) * 1024 + sI)) * 64 + d] =
                        make_float4(v0, v1, v2, v3);
                } else if constexpr (EPI == 1 || EPI == 3) {
                    float4 rv = *(const float4*)&res[(size_t)r * N + c];
                    *(float4*)&C[(size_t)r * N + c] =
                        make_float4(v0 + rv.x, v1 + rv.y, v2 + rv.z, v3 + rv.w);
                } else { // EPI == 2: relu
                    *(float4*)&C[(size_t)r * N + c] =
                        make_float4(fmaxf(v0, 0.f), fmaxf(v1, 0.f),
                                    fmaxf(v2, 0.f), fmaxf(v3, 0.f));
                }
            }
        }
    }
}

// ---------------------------------------------------------------------------
// Flash attention, fp32. One block per (b,h, 64-row q-tile). 256 threads.
// Q/K/V in head layout [(b*16+h)*1024 + s]*64 + d. Q pre-scaled by 1/8.
// LDS: 3 buffers (Q, KV time-shared, P) = 52,224 B < 64 KiB limit.
// ---------------------------------------------------------------------------
__global__ __launch_bounds__(256) void attn_k(const float* __restrict__ q,
                                              const float* __restrict__ k,
                                              const float* __restrict__ v,
                                              const int* __restrict__ mask,
                                              float* __restrict__ o)
{
    int bh = blockIdx.y;            // 0..127
    int b  = bh >> 4;
    int q0 = blockIdx.x * 64;

    const float* Q = q + (size_t)bh * (Sseq * DH);
    const float* K = k + (size_t)bh * (Sseq * DH);
    const float* V = v + (size_t)bh * (Sseq * DH);

    __shared__ __align__(16) float Qs[64][68];
    __shared__ __align__(16) float KVs[64][68];
    __shared__ __align__(16) float Ps[64][68];

    int tid = threadIdx.x;
    int ty = tid >> 4;   // 0..15 -> q rows ty*4..+3
    int tx = tid & 15;   // 0..15 -> cols tx*4..+3

    // load Q tile (scaled by 1/sqrt(dh) = 1/8)
    #pragma unroll
    for (int l = 0; l < 4; ++l) {
        int idx = tid + l * 256;     // 0..1023
        int r = idx >> 4;            // 0..63
        int c4 = (idx & 15) * 4;
        float4 t = *(const float4*)&Q[(size_t)(q0 + r) * DH + c4];
        t.x *= 0.125f; t.y *= 0.125f; t.z *= 0.125f; t.w *= 0.125f;
        *(float4*)&Qs[r][c4] = t;
    }

    float m_i[4], l_i[4], Oc[4][4];
    #pragma unroll
    for (int i = 0; i < 4; ++i) {
        m_i[i] = -1e30f; l_i[i] = 0.f;
        #pragma unroll
        for (int j = 0; j < 4; ++j) Oc[i][j] = 0.f;
    }

    for (int kt = 0; kt < Sseq; kt += 64) {
        __syncthreads();   // prev PV reads of KVs/Ps done (also covers Q load)
        // stage K tile
        #pragma unroll
        for (int l = 0; l < 4; ++l) {
            int idx = tid + l * 256;
            int r = idx >> 4;
            int c4 = (idx & 15) * 4;
            *(float4*)&KVs[r][c4] = *(const float4*)&K[(size_t)(kt + r) * DH + c4];
        }
        __syncthreads();

        // S tile: s[i][j] = sum_d Qs[qr][d] * KVs[kc][d]
        float s[4][4] = {};
        #pragma unroll
        for (int d0 = 0; d0 < 64; d0 += 4) {
            float4 qa[4], kb[4];
            #pragma unroll
            for (int i = 0; i < 4; ++i) qa[i] = *(const float4*)&Qs[ty * 4 + i][d0];
            #pragma unroll
            for (int j = 0; j < 4; ++j) kb[j] = *(const float4*)&KVs[tx * 4 + j][d0];
            #pragma unroll
            for (int i = 0; i < 4; ++i)
                #pragma unroll
                for (int j = 0; j < 4; ++j) {
                    s[i][j] = fmaf(qa[i].x, kb[j].x, s[i][j]);
                    s[i][j] = fmaf(qa[i].y, kb[j].y, s[i][j]);
                    s[i][j] = fmaf(qa[i].z, kb[j].z, s[i][j]);
                    s[i][j] = fmaf(qa[i].w, kb[j].w, s[i][j]);
                }
        }

        // mask (per k position)
        const int* mrow = mask + b * Sseq + kt;
        #pragma unroll
        for (int j = 0; j < 4; ++j) {
            if (mrow[tx * 4 + j] == 0) {
                #pragma unroll
                for (int i = 0; i < 4; ++i) s[i][j] = -1e9f;
            }
        }

        // row-wise online softmax update
        float rmax[4], rsum[4], p[4][4], al[4];
        #pragma unroll
        for (int i = 0; i < 4; ++i)
            rmax[i] = fmaxf(fmaxf(s[i][0], s[i][1]), fmaxf(s[i][2], s[i][3]));
        #pragma unroll
        for (int off = 1; off < 16; off <<= 1) {
            #pragma unroll
            for (int i = 0; i < 4; ++i)
                rmax[i] = fmaxf(rmax[i], __shfl_xor(rmax[i], off));
        }
        #pragma unroll
        for (int i = 0; i < 4; ++i) {
            float mnew = fmaxf(m_i[i], rmax[i]);
            al[i] = __expf(m_i[i] - mnew);
            m_i[i] = mnew;
            rsum[i] = 0.f;
            #pragma unroll
            for (int j = 0; j < 4; ++j) {
                p[i][j] = __expf(s[i][j] - mnew);
                rsum[i] += p[i][j];
            }
        }
        #pragma unroll
        for (int off = 1; off < 16; off <<= 1) {
            #pragma unroll
            for (int i = 0; i < 4; ++i)
                rsum[i] += __shfl_xor(rsum[i], off);
        }
        #pragma unroll
        for (int i = 0; i < 4; ++i) {
            l_i[i] = l_i[i] * al[i] + rsum[i];
            *(float4*)&Ps[ty * 4 + i][tx * 4] =
                make_float4(p[i][0], p[i][1], p[i][2], p[i][3]);
            #pragma unroll
            for (int j = 0; j < 4; ++j) Oc[i][j] *= al[i];
        }
        __syncthreads();   // S reads of KVs done; Ps fully written

        // stage V tile into the same buffer
        #pragma unroll
        for (int l = 0; l < 4; ++l) {
            int idx = tid + l * 256;
            int r = idx >> 4;
            int c4 = (idx & 15) * 4;
            *(float4*)&KVs[r][c4] = *(const float4*)&V[(size_t)(kt + r) * DH + c4];
        }
        __syncthreads();

        // PV: Oc[i][j] += sum_k Ps[qr][k] * KVs[k][dc]
        #pragma unroll
        for (int k0 = 0; k0 < 64; k0 += 4) {
            float4 pa[4], vb[4];
            #pragma unroll
            for (int i = 0; i < 4; ++i) pa[i] = *(const float4*)&Ps[ty * 4 + i][k0];
            #pragma unroll
            for (int t = 0; t < 4; ++t) vb[t] = *(const float4*)&KVs[k0 + t][tx * 4];
            #pragma unroll
            for (int i = 0; i < 4; ++i) {
                Oc[i][0] = fmaf(pa[i].x, vb[0].x, Oc[i][0]);
                Oc[i][1] = fmaf(pa[i].x, vb[0].y, Oc[i][1]);
                Oc[i][2] = fmaf(pa[i].x, vb[0].z, Oc[i][2]);
                Oc[i][3] = fmaf(pa[i].x, vb[0].w, Oc[i][3]);
                Oc[i][0] = fmaf(pa[i].y, vb[1].x, Oc[i][0]);
                Oc[i][1] = fmaf(pa[i].y, vb[1].y, Oc[i][1]);
                Oc[i][2] = fmaf(pa[i].y, vb[1].z, Oc[i][2]);
                Oc[i][3] = fmaf(pa[i].y, vb[1].w, Oc[i][3]);
                Oc[i][0] = fmaf(pa[i].z, vb[2].x, Oc[i][0]);
                Oc[i][1] = fmaf(pa[i].z, vb[2].y, Oc[i][1]);
                Oc[i][2] = fmaf(pa[i].z, vb[2].z, Oc[i][2]);
                Oc[i][3] = fmaf(pa[i].z, vb[2].w, Oc[i][3]);
                Oc[i][0] = fmaf(pa[i].w, vb[3].x, Oc[i][0]);
                Oc[i][1] = fmaf(pa[i].w, vb[3].y, Oc[i][1]);
                Oc[i][2] = fmaf(pa[i].w, vb[3].z, Oc[i][2]);
                Oc[i][3] = fmaf(pa[i].w, vb[3].w, Oc[i][3]);
            }
        }
    }

    // normalize and store (head layout, same as q)
    #pragma unroll
    for (int i = 0; i < 4; ++i) {
        float invl = 1.0f / l_i[i];
        *(float4*)&o[(size_t)bh * (Sseq * DH) + (size_t)(q0 + ty * 4 + i) * DH + tx * 4] =
            make_float4(Oc[i][0] * invl, Oc[i][1] * invl,
                        Oc[i][2] * invl, Oc[i][3] * invl);
    }
}

// ---------------------------------------------------------------------------
// Buffer plan (minimizes d_ws: only 64 MB needed; d_out doubles as scratch):
//   out_half  = d_out[0,8M)    : xn (s1-2) -> ob (s3-4) -> an (s5-6) -> out (s7)
//   attn_half = d_out[8M,16M)  : v (s2-3)  -> attn (s4..)   [output #2]
//   ws[0,8M)  : q (s2-3)   -> h1 lower (s6-7)
//   ws[8M,16M): k (s2-3)   -> h1 upper (s6-7)
// ---------------------------------------------------------------------------
extern "C" void kernel_launch(void* const* d_in, const int* in_sizes, int n_in,
                              void* d_out, int out_size, void* d_ws, size_t ws_size,
                              hipStream_t stream)
{
    const float* x     = (const float*)d_in[0];
    const int*   mask  = (const int*)  d_in[1];
    const float* wq    = (const float*)d_in[2];
    const float* bq    = (const float*)d_in[3];
    const float* wk    = (const float*)d_in[4];
    const float* bk    = (const float*)d_in[5];
    const float* wv    = (const float*)d_in[6];
    const float* bv    = (const float*)d_in[7];
    const float* wo    = (const float*)d_in[8];
    const float* bo    = (const float*)d_in[9];
    const float* w1    = (const float*)d_in[10];
    const float* b1    = (const float*)d_in[11];
    const float* w2    = (const float*)d_in[12];
    const float* b2    = (const float*)d_in[13];
    const float* g1    = (const float*)d_in[14];
    const float* beta1 = (const float*)d_in[15];
    const float* g2    = (const float*)d_in[16];
    const float* beta2 = (const float*)d_in[17];

    float* out  = (float*)d_out;             // (8,1024,1024)  first output
    float* attn = out + EIGHT_M;             // (8,1024,1024)  second output

    float* ws = (float*)d_ws;
    float* xn = out;                         // scratch in out half
    float* qb = ws;                          // 8M floats
    float* kb = ws + (size_t)EIGHT_M;        // 8M floats
    float* vb = attn;                        // scratch in attn half (dead at s4)
    float* ob = out;                         // xn dead after QKV
    float* an = out;                         // ob dead after O-proj
    float* h1 = ws;                          // 16M floats; q,k dead

    // 1. LN1
    ln_k<<<ROWS, 256, 0, stream>>>(x, g1, beta1, xn);

    // 2. QKV projections (write head layout)
    dim3 gDD(Dm / BN, ROWS / BM);            // (8, 64)
    gemm_k<0><<<gDD, 256, 0, stream>>>(xn, wq, bq, qb, nullptr, ROWS, Dm, Dm);
    gemm_k<0><<<gDD, 256, 0, stream>>>(xn, wk, bk, kb, nullptr, ROWS, Dm, Dm);
    gemm_k<0><<<gDD, 256, 0, stream>>>(xn, wv, bv, vb, nullptr, ROWS, Dm, Dm);

    // 3. flash attention (reads q,k,v; writes ob over dead xn)
    attn_k<<<dim3(Sseq / 64, Bsz * Hh), 256, 0, stream>>>(qb, kb, vb, mask, ob);

    // 4. O projection + residual -> attn (second output; vb dead)
    gemm_k<1><<<gDD, 256, 0, stream>>>(ob, wo, bo, attn, x, ROWS, Dm, Dm);

    // 5. LN2 (ob dead -> an)
    ln_k<<<ROWS, 256, 0, stream>>>(attn, g2, beta2, an);

    // 6. FFN1: relu(an @ w1 + b1) -> h1 (q,k dead)
    dim3 gDF(DFF / BN, ROWS / BM);           // (16, 64)
    gemm_k<2><<<gDF, 256, 0, stream>>>(an, w1, b1, h1, nullptr, ROWS, DFF, Dm);

    // 7. FFN2: attn + h1 @ w2 + b2 -> out (first output; an dead)
    gemm_k<3><<<gDD, 256, 0, stream>>>(h1, w2, b2, out, attn, ROWS, Dm, DFF);
}

// Round 3
// 524.245 us; speedup vs baseline: 4.6978x; 4.6978x over previous
//
#include <hip/hip_runtime.h>
#include <cstddef>
#include <cstdint>

// Problem constants
#define Bsz 8
#define Sseq 1024
#define Dm 1024
#define Hh 16
#define DH 64
#define DFF 2048
#define ROWS (Bsz*Sseq)            // 8192
#define EIGHT_M (8u*1024u*1024u)   // 8388608

typedef _Float16 f16;
typedef _Float16 f16x8 __attribute__((ext_vector_type(8)));
typedef _Float16 f16x4 __attribute__((ext_vector_type(4)));
typedef float    f32x4 __attribute__((ext_vector_type(4)));

#define MFMA16(a,b,c) __builtin_amdgcn_mfma_f32_16x16x32_f16(a, b, c, 0, 0, 0)

// global->LDS direct copy, 16B per lane. LDS dst must be wave-uniform;
// HW writes dst + lane*16. Global src is per-lane.
__device__ __forceinline__ void glds16(const void* g, void* l) {
    __builtin_amdgcn_global_load_lds(
        (const __attribute__((address_space(1))) unsigned int*)g,
        (__attribute__((address_space(3))) unsigned int*)l, 16, 0, 0);
}

// ---------------------------------------------------------------------------
// LayerNorm (fp32 in, f16 out). One block per row of 1024.
// ---------------------------------------------------------------------------
__global__ __launch_bounds__(256) void ln_k(const float* __restrict__ x,
                                            const float* __restrict__ gain,
                                            const float* __restrict__ beta,
                                            f16* __restrict__ y)
{
    int row = blockIdx.x;
    const float* xr = x + (size_t)row * Dm;
    int tid = threadIdx.x;

    float4 v = *(const float4*)&xr[tid * 4];
    float s  = v.x + v.y + v.z + v.w;
    float sq = v.x*v.x + v.y*v.y + v.z*v.z + v.w*v.w;

    #pragma unroll
    for (int off = 32; off > 0; off >>= 1) {
        s  += __shfl_down(s,  off);
        sq += __shfl_down(sq, off);
    }
    __shared__ float ss[4], ssq[4];
    int w = tid >> 6, ln = tid & 63;
    if (ln == 0) { ss[w] = s; ssq[w] = sq; }
    __syncthreads();
    float S  = ss[0] + ss[1] + ss[2] + ss[3];
    float SQ = ssq[0] + ssq[1] + ssq[2] + ssq[3];

    float mean = S * (1.0f / 1024.0f);
    float var  = (SQ - 1024.0f * mean * mean) * (1.0f / 1023.0f);
    var = fmaxf(var, 0.0f);
    float inv = 1.0f / (sqrtf(var) + 1e-6f);

    float4 gv = *(const float4*)&gain[tid * 4];
    float4 bv = *(const float4*)&beta[tid * 4];
    f16x4 o;
    o[0] = (f16)(gv.x * inv * (v.x - mean) + bv.x);
    o[1] = (f16)(gv.y * inv * (v.y - mean) + bv.y);
    o[2] = (f16)(gv.z * inv * (v.z - mean) + bv.z);
    o[3] = (f16)(gv.w * inv * (v.w - mean) + bv.w);
    *(f16x4*)&y[(size_t)row * Dm + tid * 4] = o;
}

// ---------------------------------------------------------------------------
// Weight transpose+cast: src fp32 [K][N] -> dst f16 [N][K]  ("B^T" layout)
// ---------------------------------------------------------------------------
__global__ __launch_bounds__(256) void transcast_k(const float* __restrict__ src,
                                                   f16* __restrict__ dst,
                                                   int K, int N)
{
    __shared__ float t[32][33];
    int n0 = blockIdx.x * 32, k0 = blockIdx.y * 32;
    int tx = threadIdx.x & 31, ty = threadIdx.x >> 5;   // ty 0..7
    #pragma unroll
    for (int i = 0; i < 4; ++i)
        t[ty + 8*i][tx] = src[(size_t)(k0 + ty + 8*i) * N + n0 + tx];
    __syncthreads();
    #pragma unroll
    for (int i = 0; i < 4; ++i)
        dst[(size_t)(n0 + ty + 8*i) * K + k0 + tx] = (f16)t[tx][ty + 8*i];
}

// ---------------------------------------------------------------------------
// V head-layout [bh][s][d] -> V^T [bh][d][s]  (f16)
// ---------------------------------------------------------------------------
__global__ __launch_bounds__(256) void vtrans_k(const f16* __restrict__ v,
                                                f16* __restrict__ vt)
{
    int bh = blockIdx.y;
    int s0 = blockIdx.x * 64;
    __shared__ f16 t[64][72];
    int tid = threadIdx.x;
    int sl = tid >> 2, dq = (tid & 3) * 16;
    const f16* src = v + ((size_t)bh * Sseq + s0 + sl) * DH + dq;
    *(f16x8*)&t[sl][dq]     = *(const f16x8*)&src[0];
    *(f16x8*)&t[sl][dq + 8] = *(const f16x8*)&src[8];
    __syncthreads();
    int d = tid >> 2, sq = (tid & 3) * 16;
    f16 buf[16];
    #pragma unroll
    for (int i = 0; i < 16; ++i) buf[i] = t[sq + i][d];
    f16* dst = vt + ((size_t)bh * DH + d) * Sseq + s0 + sq;
    *(f16x8*)&dst[0] = *(f16x8*)&buf[0];
    *(f16x8*)&dst[8] = *(f16x8*)&buf[8];
}

// ---------------------------------------------------------------------------
// f16 MFMA GEMM (m97 structure): 128x128 tile, BK=32, 4 waves (2x2 of 64x64),
// single-buffer LDS, global_load_lds staging, 16 MFMA/wave/K-step.
// A row-major [M][K] f16; Bt = B^T [N][K] f16. bias fp32.
// EPI 0: head-layout f16 out, * scale (QKV)
// EPI 1: fp32 out + fp32 residual    (O-proj, FFN2)
// EPI 2: relu -> f16 row-major       (FFN1)
// ---------------------------------------------------------------------------
template<int EPI>
__global__ __launch_bounds__(256) void gemm_k(const f16* __restrict__ A,
                                              const f16* __restrict__ Bt,
                                              const float* __restrict__ bias,
                                              void* __restrict__ Cv,
                                              const float* __restrict__ res,
                                              float scale, int M, int N, int K)
{
    __shared__ f16 As[128 * 32];
    __shared__ f16 Bs[128 * 32];

    int tid  = threadIdx.x;
    int lane = tid & 63, w = tid >> 6;
    int wr = w >> 1, wc = w & 1;
    int lr = lane & 15, lg = lane >> 4;
    int m0 = blockIdx.y * 128, n0 = blockIdx.x * 128;

    f32x4 acc[4][4];
    #pragma unroll
    for (int i = 0; i < 4; ++i)
        #pragma unroll
        for (int j = 0; j < 4; ++j)
            acc[i][j] = (f32x4){0.f, 0.f, 0.f, 0.f};

    int srow = lane >> 2;         // 0..15 row-in-chunk
    int sk   = (lane & 3) * 8;    // k offset (8 f16 = 16B)

    for (int k0 = 0; k0 < K; k0 += 32) {
        #pragma unroll
        for (int c = 0; c < 2; ++c) {
            int ch = 2 * w + c;   // 0..7, wave-uniform
            glds16(A  + (size_t)(m0 + ch * 16 + srow) * K + k0 + sk, As + ch * 512);
            glds16(Bt + (size_t)(n0 + ch * 16 + srow) * K + k0 + sk, Bs + ch * 512);
        }
        __syncthreads();

        f16x8 af[4], bf[4];
        #pragma unroll
        for (int mi = 0; mi < 4; ++mi)
            af[mi] = *(const f16x8*)&As[(wr * 64 + mi * 16 + lr) * 32 + lg * 8];
        #pragma unroll
        for (int ni = 0; ni < 4; ++ni)
            bf[ni] = *(const f16x8*)&Bs[(wc * 64 + ni * 16 + lr) * 32 + lg * 8];
        #pragma unroll
        for (int mi = 0; mi < 4; ++mi)
            #pragma unroll
            for (int ni = 0; ni < 4; ++ni)
                acc[mi][ni] = MFMA16(af[mi], bf[ni], acc[mi][ni]);
        __syncthreads();
    }

    // epilogue: lane holds C[row = lg*4+r][col = lr] per 16x16 frag
    #pragma unroll
    for (int mi = 0; mi < 4; ++mi) {
        #pragma unroll
        for (int r = 0; r < 4; ++r) {
            int gm = m0 + wr * 64 + mi * 16 + lg * 4 + r;
            #pragma unroll
            for (int ni = 0; ni < 4; ++ni) {
                int gn = n0 + wc * 64 + ni * 16 + lr;
                float vacc = acc[mi][ni][r] + bias[gn];
                if constexpr (EPI == 0) {
                    int b = gm >> 10, s = gm & 1023;
                    int h = gn >> 6,  d = gn & 63;
                    ((f16*)Cv)[(((size_t)(b * 16 + h) * 1024 + s) << 6) + d] =
                        (f16)(vacc * scale);
                } else if constexpr (EPI == 1) {
                    ((float*)Cv)[(size_t)gm * N + gn] =
                        vacc + res[(size_t)gm * N + gn];
                } else {
                    ((f16*)Cv)[(size_t)gm * N + gn] = (f16)fmaxf(vacc, 0.f);
                }
            }
        }
    }
}

// ---------------------------------------------------------------------------
// MFMA flash attention. Block = (q-tile of 64) x (b,h). 4 waves; wave w owns
// q rows [w*16, w*16+16) -> fully independent online softmax per wave.
// K LDS [kv][d], Vt LDS [d][kv], both XOR-swizzled (16B unit ^ (row&7)) via
// pre-swizzled global source (linear glds dest) + swizzled ds_read.
// Q fragments live in registers. P re-fragmented through padded per-wave LDS.
// Output: row-major [B*S][D] f16.
// ---------------------------------------------------------------------------
__global__ __launch_bounds__(256) void attn_k(const f16* __restrict__ q,
                                              const f16* __restrict__ k,
                                              const f16* __restrict__ vt,
                                              const int* __restrict__ mask,
                                              f16* __restrict__ o)
{
    int bh = blockIdx.y;          // 0..127
    int b  = bh >> 4, h = bh & 15;
    int q0 = blockIdx.x * 64;

    const f16* Qb = q  + (size_t)bh * (Sseq * DH);   // [s][d]
    const f16* Kb = k  + (size_t)bh * (Sseq * DH);   // [s][d]
    const f16* Vb = vt + (size_t)bh * (DH * Sseq);   // [d][s]

    __shared__ f16 Ks[64 * 64];      // [kv][d] swizzled
    __shared__ f16 Vts[64 * 64];     // [d][kv] swizzled
    __shared__ f16 Ps[4][16][72];    // per-wave P, padded rows (144B)

    int tid  = threadIdx.x;
    int lane = tid & 63, w = tid >> 6;
    int lr = lane & 15, lg = lane >> 4;

    // Q A-fragments in registers (Q pre-scaled by 1/8 at projection)
    f16x8 qf[2];
    {
        const f16* qr = Qb + (size_t)(q0 + w * 16 + lr) * DH + lg * 8;
        qf[0] = *(const f16x8*)&qr[0];
        qf[1] = *(const f16x8*)&qr[32];
    }

    f32x4 oacc[4];
    #pragma unroll
    for (int ni = 0; ni < 4; ++ni) oacc[ni] = (f32x4){0.f, 0.f, 0.f, 0.f};
    float m_i[4], l_i[4];
    #pragma unroll
    for (int r = 0; r < 4; ++r) { m_i[r] = -1e30f; l_i[r] = 0.f; }

    int srow8 = lane >> 3;        // 0..7 row-in-chunk
    int sc16  = lane & 7;         // 16B unit in row

    for (int t0 = 0; t0 < Sseq; t0 += 64) {
        // stage K and Vt (8 chunks each of 8 rows x 128B); wave w: chunks 2w,2w+1
        #pragma unroll
        for (int c = 0; c < 2; ++c) {
            int ch  = 2 * w + c;
            int row = ch * 8 + srow8;
            int cs  = sc16 ^ (row & 7);   // inverse-swizzled source unit
            glds16(Kb + (size_t)(t0 + row) * DH + cs * 8,  Ks  + ch * 512);
            glds16(Vb + (size_t)row * Sseq + t0 + cs * 8,  Vts + ch * 512);
        }
        __syncthreads();

        // S = (Q/8) @ K^T : per wave 4 col-frags x 2 k-steps
        f32x4 s[4];
        #pragma unroll
        for (int ni = 0; ni < 4; ++ni) s[ni] = (f32x4){0.f, 0.f, 0.f, 0.f};
        #pragma unroll
        for (int ks = 0; ks < 2; ++ks) {
            #pragma unroll
            for (int ni = 0; ni < 4; ++ni) {
                int row = ni * 16 + lr;
                f16x8 kf = *(const f16x8*)
                    &Ks[row * 64 + ((((ks << 2) | lg) ^ (row & 7)) << 3)];
                s[ni] = MFMA16(qf[ks], kf, s[ni]);
            }
        }

        // mask (scores already scaled)
        const int* mrow = mask + b * Sseq + t0;
        #pragma unroll
        for (int ni = 0; ni < 4; ++ni) {
            if (mrow[ni * 16 + lr] == 0) {
                #pragma unroll
                for (int r = 0; r < 4; ++r) s[ni][r] = -1e9f;
            }
        }

        // online softmax (rows lg*4+r, values spread over 16 lanes x 4 ni)
        float pmax[4];
        #pragma unroll
        for (int r = 0; r < 4; ++r)
            pmax[r] = fmaxf(fmaxf(s[0][r], s[1][r]), fmaxf(s[2][r], s[3][r]));
        #pragma unroll
        for (int off = 1; off < 16; off <<= 1) {
            #pragma unroll
            for (int r = 0; r < 4; ++r)
                pmax[r] = fmaxf(pmax[r], __shfl_xor(pmax[r], off));
        }

        float p[4][4], rsum[4], alpha[4];
        #pragma unroll
        for (int r = 0; r < 4; ++r) {
            float mnew = fmaxf(m_i[r], pmax[r]);
            alpha[r] = __expf(m_i[r] - mnew);
            m_i[r] = mnew;
            rsum[r] = 0.f;
            #pragma unroll
            for (int ni = 0; ni < 4; ++ni) {
                p[ni][r] = __expf(s[ni][r] - mnew);
                rsum[r] += p[ni][r];
            }
        }
        #pragma unroll
        for (int off = 1; off < 16; off <<= 1) {
            #pragma unroll
            for (int r = 0; r < 4; ++r)
                rsum[r] += __shfl_xor(rsum[r], off);
        }
        #pragma unroll
        for (int r = 0; r < 4; ++r) {
            l_i[r] = l_i[r] * alpha[r] + rsum[r];
            #pragma unroll
            for (int ni = 0; ni < 4; ++ni) {
                Ps[w][lg * 4 + r][ni * 16 + lr] = (f16)p[ni][r];
                oacc[ni][r] *= alpha[r];
            }
        }

        // PV: O += P @ V  (A-frag from own-wave Ps; B-frag from swizzled Vts)
        #pragma unroll
        for (int ks = 0; ks < 2; ++ks) {
            f16x8 pf = *(const f16x8*)&Ps[w][lr][ks * 32 + lg * 8];
            #pragma unroll
            for (int ni = 0; ni < 4; ++ni) {
                int row = ni * 16 + lr;
                f16x8 vf = *(const f16x8*)
                    &Vts[row * 64 + ((((ks << 2) | lg) ^ (row & 7)) << 3)];
                oacc[ni] = MFMA16(pf, vf, oacc[ni]);
            }
        }
        __syncthreads();   // all waves done with Ks/Vts before restage
    }

    // normalize, store row-major [b*1024+s][h*64+d] f16
    size_t rbase = (size_t)b * Sseq + q0 + w * 16;
    #pragma unroll
    for (int r = 0; r < 4; ++r) {
        float inv = 1.0f / l_i[r];
        #pragma unroll
        for (int ni = 0; ni < 4; ++ni)
            o[(rbase + lg * 4 + r) * Dm + h * 64 + ni * 16 + lr] =
                (f16)(oacc[ni][r] * inv);
    }
}

// ---------------------------------------------------------------------------
// Buffer plan (d_ws = 32M f16 = 64MB, proven available; d_out out-half doubles
// as V / V^T scratch until the final FFN2 write):
//   ws f16 [0,8M):   wqT,wkT,wvT,woT (1M ea) | w1T @4M (2M) | w2T @6M (2M)
//   ws f16 [8M,16M): xn -> ob -> an
//   ws f16 [16M,32M): q,k -> h1 (16M)
//   d_out out-half:  v (8M f16) + vt (8M f16) -> final out (fp32)
//   d_out attn-half: attn fp32 (output #2) from step 6 on
// ---------------------------------------------------------------------------
extern "C" void kernel_launch(void* const* d_in, const int* in_sizes, int n_in,
                              void* d_out, int out_size, void* d_ws, size_t ws_size,
                              hipStream_t stream)
{
    const float* x     = (const float*)d_in[0];
    const int*   mask  = (const int*)  d_in[1];
    const float* wq    = (const float*)d_in[2];
    const float* bq    = (const float*)d_in[3];
    const float* wk    = (const float*)d_in[4];
    const float* bk    = (const float*)d_in[5];
    const float* wv    = (const float*)d_in[6];
    const float* bv    = (const float*)d_in[7];
    const float* wo    = (const float*)d_in[8];
    const float* bo    = (const float*)d_in[9];
    const float* w1    = (const float*)d_in[10];
    const float* b1    = (const float*)d_in[11];
    const float* w2    = (const float*)d_in[12];
    const float* b2    = (const float*)d_in[13];
    const float* g1    = (const float*)d_in[14];
    const float* beta1 = (const float*)d_in[15];
    const float* g2    = (const float*)d_in[16];
    const float* beta2 = (const float*)d_in[17];

    float* out  = (float*)d_out;
    float* attn = out + EIGHT_M;

    const size_t M1 = 1024 * 1024;
    f16* ws16 = (f16*)d_ws;
    f16* wqT = ws16 + 0 * M1;
    f16* wkT = ws16 + 1 * M1;
    f16* wvT = ws16 + 2 * M1;
    f16* woT = ws16 + 3 * M1;
    f16* w1T = ws16 + 4 * M1;      // [2048][1024]
    f16* w2T = ws16 + 6 * M1;      // [1024][2048]
    f16* xn  = ws16 + 8 * M1;      // 8M
    f16* ob  = xn;                 // alias (xn dead after QKV)
    f16* an  = xn;                 // alias (ob dead after O-proj)
    f16* qh  = ws16 + 16 * M1;     // 8M
    f16* kh  = ws16 + 24 * M1;     // 8M
    f16* h1  = qh;                 // 16M (q,k dead)
    f16* vh  = (f16*)d_out;        // out-half scratch (dead before final write)
    f16* vth = vh + 8 * M1;

    dim3 tb(256);

    // 0. weight prep (cast + transpose to [N][K] f16)
    transcast_k<<<dim3(32, 32), tb, 0, stream>>>(wq, wqT, 1024, 1024);
    transcast_k<<<dim3(32, 32), tb, 0, stream>>>(wk, wkT, 1024, 1024);
    transcast_k<<<dim3(32, 32), tb, 0, stream>>>(wv, wvT, 1024, 1024);
    transcast_k<<<dim3(32, 32), tb, 0, stream>>>(wo, woT, 1024, 1024);
    transcast_k<<<dim3(64, 32), tb, 0, stream>>>(w1, w1T, 1024, 2048);
    transcast_k<<<dim3(32, 64), tb, 0, stream>>>(w2, w2T, 2048, 1024);

    // 1. LN1
    ln_k<<<ROWS, tb, 0, stream>>>(x, g1, beta1, xn);

    // 2. QKV projections (head layout f16; Q pre-scaled by 1/8)
    dim3 gDD(1024 / 128, ROWS / 128);    // (8, 64)
    gemm_k<0><<<gDD, tb, 0, stream>>>(xn, wqT, bq, qh, nullptr, 0.125f, ROWS, Dm, Dm);
    gemm_k<0><<<gDD, tb, 0, stream>>>(xn, wkT, bk, kh, nullptr, 1.0f,   ROWS, Dm, Dm);
    gemm_k<0><<<gDD, tb, 0, stream>>>(xn, wvT, bv, vh, nullptr, 1.0f,   ROWS, Dm, Dm);

    // 3. V -> V^T per head
    vtrans_k<<<dim3(16, 128), tb, 0, stream>>>(vh, vth);

    // 4. flash attention -> ob row-major f16
    attn_k<<<dim3(16, 128), tb, 0, stream>>>(qh, kh, vth, mask, ob);

    // 5. O projection + residual -> attn (fp32, output #2)
    gemm_k<1><<<gDD, tb, 0, stream>>>(ob, woT, bo, attn, x, 1.0f, ROWS, Dm, Dm);

    // 6. LN2 -> an f16
    ln_k<<<ROWS, tb, 0, stream>>>(attn, g2, beta2, an);

    // 7. FFN1: relu(an @ w1 + b1) -> h1 f16
    dim3 gDF(2048 / 128, ROWS / 128);    // (16, 64)
    gemm_k<2><<<gDF, tb, 0, stream>>>(an, w1T, b1, h1, nullptr, 1.0f, ROWS, DFF, Dm);

    // 8. FFN2: attn + h1 @ w2 + b2 -> out (fp32, output #1)
    gemm_k<1><<<gDD, tb, 0, stream>>>(h1, w2T, b2, out, attn, 1.0f, ROWS, Dm, DFF);
}

// Round 4
// 510.091 us; speedup vs baseline: 4.8281x; 1.0277x over previous
//
#include <hip/hip_runtime.h>
#include <cstddef>
#include <cstdint>

// Problem constants
#define Bsz 8
#define Sseq 1024
#define Dm 1024
#define Hh 16
#define DH 64
#define DFF 2048
#define ROWS (Bsz*Sseq)            // 8192
#define EIGHT_M (8u*1024u*1024u)   // 8388608

#define QSCALE 0.180336880f        // 0.125 * log2(e) — folds softmax base-2

typedef _Float16 f16;
typedef _Float16 f16x8 __attribute__((ext_vector_type(8)));
typedef _Float16 f16x4 __attribute__((ext_vector_type(4)));
typedef float    f32x4 __attribute__((ext_vector_type(4)));

#define MFMA16(a,b,c) __builtin_amdgcn_mfma_f32_16x16x32_f16(a, b, c, 0, 0, 0)

// global->LDS direct copy, 16B per lane. LDS dst wave-uniform base; HW writes
// dst + lane*16. Global src per-lane.
__device__ __forceinline__ void glds16(const void* g, void* l) {
    __builtin_amdgcn_global_load_lds(
        (const __attribute__((address_space(1))) unsigned int*)g,
        (__attribute__((address_space(3))) unsigned int*)l, 16, 0, 0);
}

// ---------------------------------------------------------------------------
// LayerNorm (fp32 in, f16 out). One block per row of 1024.
// ---------------------------------------------------------------------------
__global__ __launch_bounds__(256) void ln_k(const float* __restrict__ x,
                                            const float* __restrict__ gain,
                                            const float* __restrict__ beta,
                                            f16* __restrict__ y)
{
    int row = blockIdx.x;
    const float* xr = x + (size_t)row * Dm;
    int tid = threadIdx.x;

    float4 v = *(const float4*)&xr[tid * 4];
    float s  = v.x + v.y + v.z + v.w;
    float sq = v.x*v.x + v.y*v.y + v.z*v.z + v.w*v.w;

    #pragma unroll
    for (int off = 32; off > 0; off >>= 1) {
        s  += __shfl_down(s,  off);
        sq += __shfl_down(sq, off);
    }
    __shared__ float ss[4], ssq[4];
    int w = tid >> 6, ln = tid & 63;
    if (ln == 0) { ss[w] = s; ssq[w] = sq; }
    __syncthreads();
    float S  = ss[0] + ss[1] + ss[2] + ss[3];
    float SQ = ssq[0] + ssq[1] + ssq[2] + ssq[3];

    float mean = S * (1.0f / 1024.0f);
    float var  = (SQ - 1024.0f * mean * mean) * (1.0f / 1023.0f);
    var = fmaxf(var, 0.0f);
    float inv = 1.0f / (sqrtf(var) + 1e-6f);

    float4 gv = *(const float4*)&gain[tid * 4];
    float4 bv = *(const float4*)&beta[tid * 4];
    f16x4 o;
    o[0] = (f16)(gv.x * inv * (v.x - mean) + bv.x);
    o[1] = (f16)(gv.y * inv * (v.y - mean) + bv.y);
    o[2] = (f16)(gv.z * inv * (v.z - mean) + bv.z);
    o[3] = (f16)(gv.w * inv * (v.w - mean) + bv.w);
    *(f16x4*)&y[(size_t)row * Dm + tid * 4] = o;
}

// ---------------------------------------------------------------------------
// Weight transpose+cast+scale: src fp32 [K][N] -> dst f16 [N][K]
// ---------------------------------------------------------------------------
__global__ __launch_bounds__(256) void transcast_k(const float* __restrict__ src,
                                                   f16* __restrict__ dst,
                                                   int K, int N, float scale)
{
    __shared__ float t[32][33];
    int n0 = blockIdx.x * 32, k0 = blockIdx.y * 32;
    int tx = threadIdx.x & 31, ty = threadIdx.x >> 5;   // ty 0..7
    #pragma unroll
    for (int i = 0; i < 4; ++i)
        t[ty + 8*i][tx] = src[(size_t)(k0 + ty + 8*i) * N + n0 + tx];
    __syncthreads();
    #pragma unroll
    for (int i = 0; i < 4; ++i)
        dst[(size_t)(n0 + ty + 8*i) * K + k0 + tx] = (f16)(t[tx][ty + 8*i] * scale);
}

// ---------------------------------------------------------------------------
// Bias concat: bcat[0:1024)=bq*QSCALE, [1024:2048)=bk, [2048:3072)=bv
// ---------------------------------------------------------------------------
__global__ __launch_bounds__(256) void biascat_k(const float* __restrict__ bq,
                                                 const float* __restrict__ bk,
                                                 const float* __restrict__ bv,
                                                 float* __restrict__ bcat)
{
    int i = blockIdx.x * 256 + threadIdx.x;   // 0..3071
    float v;
    if (i < 1024)       v = bq[i] * QSCALE;
    else if (i < 2048)  v = bk[i - 1024];
    else                v = bv[i - 2048];
    bcat[i] = v;
}

// ---------------------------------------------------------------------------
// V head-layout [bh][s][d] -> V^T [bh][d][s]  (f16)
// ---------------------------------------------------------------------------
__global__ __launch_bounds__(256) void vtrans_k(const f16* __restrict__ v,
                                                f16* __restrict__ vt)
{
    int bh = blockIdx.y;
    int s0 = blockIdx.x * 64;
    __shared__ f16 t[64][72];
    int tid = threadIdx.x;
    int sl = tid >> 2, dq = (tid & 3) * 16;
    const f16* src = v + ((size_t)bh * Sseq + s0 + sl) * DH + dq;
    *(f16x8*)&t[sl][dq]     = *(const f16x8*)&src[0];
    *(f16x8*)&t[sl][dq + 8] = *(const f16x8*)&src[8];
    __syncthreads();
    int d = tid >> 2, sq = (tid & 3) * 16;
    f16 buf[16];
    #pragma unroll
    for (int i = 0; i < 16; ++i) buf[i] = t[sq + i][d];
    f16* dst = vt + ((size_t)bh * DH + d) * Sseq + s0 + sq;
    *(f16x8*)&dst[0] = *(f16x8*)&buf[0];
    *(f16x8*)&dst[8] = *(f16x8*)&buf[8];
}

// ---------------------------------------------------------------------------
// f16 MFMA GEMM, 2-phase double-buffered (T3 minimum recipe):
//   BM=256, BN=128, BK=32, 512 threads (8 waves, 4x2 of 64x64).
//   LDS 48KB: As[2][256*32], Bs[2][128*32].
//   Per K-step: issue global_load_lds for tile t+1 FIRST, then ds_read+MFMA
//   of tile t, then one __syncthreads() (drains vmcnt(0) -> next tile ready).
// A row-major [M][K] f16; Bt = B^T [N][K] f16; bias fp32[N].
// EPI 0: fused QKV -> head-layout f16, dest C0/C1/C2 selected by n0>>10
// EPI 1: fp32 out + fp32 residual    (O-proj, FFN2)
// EPI 2: relu -> f16 row-major       (FFN1)
// ---------------------------------------------------------------------------
template<int EPI>
__global__ __launch_bounds__(512) void gemm2_k(const f16* __restrict__ A,
                                               const f16* __restrict__ Bt,
                                               const float* __restrict__ bias,
                                               void* __restrict__ C0,
                                               void* __restrict__ C1,
                                               void* __restrict__ C2,
                                               const float* __restrict__ res,
                                               int M, int N, int K)
{
    __shared__ f16 As[2][256 * 32];   // 16KB per buffer
    __shared__ f16 Bs[2][128 * 32];   // 8KB per buffer

    int tid  = threadIdx.x;
    int lane = tid & 63, w = tid >> 6;      // w 0..7
    int wr = w >> 1, wc = w & 1;            // wave tile: rows wr*64, cols wc*64
    int lr = lane & 15, lg = lane >> 4;
    int m0 = blockIdx.y * 256, n0 = blockIdx.x * 128;

    // staging chunk ids (16B chunks; 4 chunks per 32-f16 row)
    int cA0 = w * 64 + lane;          // 0..511   (A rows 0..127)
    int cA1 = cA0 + 512;              // 512..1023 (A rows 128..255)
    int cB  = w * 64 + lane;          // 0..511   (B rows 0..127)
    const f16* Ag0 = A  + (size_t)(m0 + (cA0 >> 2)) * K + (cA0 & 3) * 8;
    const f16* Ag1 = A  + (size_t)(m0 + (cA1 >> 2)) * K + (cA1 & 3) * 8;
    const f16* Bg  = Bt + (size_t)(n0 + (cB  >> 2)) * K + (cB  & 3) * 8;

    f32x4 acc[4][4];
    #pragma unroll
    for (int i = 0; i < 4; ++i)
        #pragma unroll
        for (int j = 0; j < 4; ++j)
            acc[i][j] = (f32x4){0.f, 0.f, 0.f, 0.f};

    int aoff[4], boff[4];
    #pragma unroll
    for (int mi = 0; mi < 4; ++mi) aoff[mi] = (wr * 64 + mi * 16 + lr) * 32 + lg * 8;
    #pragma unroll
    for (int ni = 0; ni < 4; ++ni) boff[ni] = (wc * 64 + ni * 16 + lr) * 32 + lg * 8;

    // prologue: stage tile 0 into buffer 0
    glds16(Ag0, &As[0][w * 512]);
    glds16(Ag1, &As[0][4096 + w * 512]);
    glds16(Bg,  &Bs[0][w * 512]);
    __syncthreads();

    int nt = K >> 5;    // K/32
    int cur = 0;
    for (int t = 0; t < nt; ++t) {
        if (t + 1 < nt) {          // issue next-tile loads BEFORE compute
            int nb = cur ^ 1;
            int ko = (t + 1) * 32;
            glds16(Ag0 + ko, &As[nb][w * 512]);
            glds16(Ag1 + ko, &As[nb][4096 + w * 512]);
            glds16(Bg  + ko, &Bs[nb][w * 512]);
        }
        f16x8 af[4], bf[4];
        #pragma unroll
        for (int mi = 0; mi < 4; ++mi) af[mi] = *(const f16x8*)&As[cur][aoff[mi]];
        #pragma unroll
        for (int ni = 0; ni < 4; ++ni) bf[ni] = *(const f16x8*)&Bs[cur][boff[ni]];
        #pragma unroll
        for (int mi = 0; mi < 4; ++mi)
            #pragma unroll
            for (int ni = 0; ni < 4; ++ni)
                acc[mi][ni] = MFMA16(af[mi], bf[ni], acc[mi][ni]);
        __syncthreads();          // drains vmcnt(0): tile t+1 landed; all reads of cur done
        cur ^= 1;
    }

    // epilogue: lane holds C[row=lg*4+r][col=lr] per 16x16 frag
    if constexpr (EPI == 0) {
        int seg = n0 >> 10;                 // uniform per block (128 | 1024)
        f16* dst = (seg == 0) ? (f16*)C0 : ((seg == 1) ? (f16*)C1 : (f16*)C2);
        int nn0 = n0 & 1023;
        #pragma unroll
        for (int mi = 0; mi < 4; ++mi)
            #pragma unroll
            for (int r = 0; r < 4; ++r) {
                int gm = m0 + wr * 64 + mi * 16 + lg * 4 + r;
                int b = gm >> 10, s = gm & 1023;
                #pragma unroll
                for (int ni = 0; ni < 4; ++ni) {
                    int n = nn0 + wc * 64 + ni * 16 + lr;
                    int h = n >> 6, d = n & 63;
                    float v = acc[mi][ni][r] + bias[n0 + wc * 64 + ni * 16 + lr];
                    dst[(((size_t)(b * 16 + h) * 1024 + s) << 6) + d] = (f16)v;
                }
            }
    } else {
        #pragma unroll
        for (int mi = 0; mi < 4; ++mi)
            #pragma unroll
            for (int r = 0; r < 4; ++r) {
                int gm = m0 + wr * 64 + mi * 16 + lg * 4 + r;
                #pragma unroll
                for (int ni = 0; ni < 4; ++ni) {
                    int gn = n0 + wc * 64 + ni * 16 + lr;
                    float v = acc[mi][ni][r] + bias[gn];
                    if constexpr (EPI == 1) {
                        ((float*)C0)[(size_t)gm * N + gn] =
                            v + res[(size_t)gm * N + gn];
                    } else {
                        ((f16*)C0)[(size_t)gm * N + gn] = (f16)fmaxf(v, 0.f);
                    }
                }
            }
    }
}

// ---------------------------------------------------------------------------
// MFMA flash attention (log2-domain softmax + defer-max). Block = 64 q-rows x
// (b,h). 4 waves; wave w owns q rows [w*16, w*16+16). Q pre-scaled by
// 0.125*log2e at projection -> p = exp2(s - m). XOR-swizzled K/Vt staging.
// ---------------------------------------------------------------------------
__global__ __launch_bounds__(256) void attn_k(const f16* __restrict__ q,
                                              const f16* __restrict__ k,
                                              const f16* __restrict__ vt,
                                              const int* __restrict__ mask,
                                              f16* __restrict__ o)
{
    int bh = blockIdx.y;          // 0..127
    int b  = bh >> 4, h = bh & 15;
    int q0 = blockIdx.x * 64;

    const f16* Qb = q  + (size_t)bh * (Sseq * DH);   // [s][d]
    const f16* Kb = k  + (size_t)bh * (Sseq * DH);   // [s][d]
    const f16* Vb = vt + (size_t)bh * (DH * Sseq);   // [d][s]

    __shared__ f16 Ks[64 * 64];      // [kv][d] swizzled
    __shared__ f16 Vts[64 * 64];     // [d][kv] swizzled
    __shared__ f16 Ps[4][16][72];    // per-wave P, padded rows

    int tid  = threadIdx.x;
    int lane = tid & 63, w = tid >> 6;
    int lr = lane & 15, lg = lane >> 4;

    f16x8 qf[2];
    {
        const f16* qr = Qb + (size_t)(q0 + w * 16 + lr) * DH + lg * 8;
        qf[0] = *(const f16x8*)&qr[0];
        qf[1] = *(const f16x8*)&qr[32];
    }

    f32x4 oacc[4];
    #pragma unroll
    for (int ni = 0; ni < 4; ++ni) oacc[ni] = (f32x4){0.f, 0.f, 0.f, 0.f};
    float m_i[4], l_i[4];
    #pragma unroll
    for (int r = 0; r < 4; ++r) { m_i[r] = -1e30f; l_i[r] = 0.f; }

    int srow8 = lane >> 3;        // 0..7 row-in-chunk
    int sc16  = lane & 7;         // 16B unit in row

    for (int t0 = 0; t0 < Sseq; t0 += 64) {
        #pragma unroll
        for (int c = 0; c < 2; ++c) {
            int ch  = 2 * w + c;
            int row = ch * 8 + srow8;
            int cs  = sc16 ^ (row & 7);   // inverse-swizzled source unit
            glds16(Kb + (size_t)(t0 + row) * DH + cs * 8,  Ks  + ch * 512);
            glds16(Vb + (size_t)row * Sseq + t0 + cs * 8,  Vts + ch * 512);
        }
        __syncthreads();

        // S = Q @ K^T (already in log2 units)
        f32x4 s[4];
        #pragma unroll
        for (int ni = 0; ni < 4; ++ni) s[ni] = (f32x4){0.f, 0.f, 0.f, 0.f};
        #pragma unroll
        for (int ks = 0; ks < 2; ++ks) {
            #pragma unroll
            for (int ni = 0; ni < 4; ++ni) {
                int row = ni * 16 + lr;
                f16x8 kf = *(const f16x8*)
                    &Ks[row * 64 + ((((ks << 2) | lg) ^ (row & 7)) << 3)];
                s[ni] = MFMA16(qf[ks], kf, s[ni]);
            }
        }

        // mask
        const int* mrow = mask + b * Sseq + t0;
        #pragma unroll
        for (int ni = 0; ni < 4; ++ni) {
            if (mrow[ni * 16 + lr] == 0) {
                #pragma unroll
                for (int r = 0; r < 4; ++r) s[ni][r] = -1e9f;
            }
        }

        // row max (16-lane lr-group reduce)
        float pmax[4];
        #pragma unroll
        for (int r = 0; r < 4; ++r)
            pmax[r] = fmaxf(fmaxf(s[0][r], s[1][r]), fmaxf(s[2][r], s[3][r]));
        #pragma unroll
        for (int off = 1; off < 16; off <<= 1) {
            #pragma unroll
            for (int r = 0; r < 4; ++r)
                pmax[r] = fmaxf(pmax[r], __shfl_xor(pmax[r], off));
        }

        // T13 defer-max: only rescale when max grew by > 8 (log2 units)
        bool need = false;
        #pragma unroll
        for (int r = 0; r < 4; ++r) need = need || (pmax[r] > m_i[r] + 8.0f);
        if (__any(need)) {
            #pragma unroll
            for (int r = 0; r < 4; ++r) {
                float mnew = fmaxf(m_i[r], pmax[r]);
                float al = exp2f(m_i[r] - mnew);
                m_i[r] = mnew;
                l_i[r] *= al;
                #pragma unroll
                for (int ni = 0; ni < 4; ++ni) oacc[ni][r] *= al;
            }
        }

        // p = exp2(s - m), bounded by 2^8
        float rsum[4];
        #pragma unroll
        for (int r = 0; r < 4; ++r) {
            rsum[r] = 0.f;
            #pragma unroll
            for (int ni = 0; ni < 4; ++ni) {
                float p = exp2f(s[ni][r] - m_i[r]);
                Ps[w][lg * 4 + r][ni * 16 + lr] = (f16)p;
                rsum[r] += p;
            }
        }
        #pragma unroll
        for (int off = 1; off < 16; off <<= 1) {
            #pragma unroll
            for (int r = 0; r < 4; ++r)
                rsum[r] += __shfl_xor(rsum[r], off);
        }
        #pragma unroll
        for (int r = 0; r < 4; ++r) l_i[r] += rsum[r];

        // PV: O += P @ V
        #pragma unroll
        for (int ks = 0; ks < 2; ++ks) {
            f16x8 pf = *(const f16x8*)&Ps[w][lr][ks * 32 + lg * 8];
            #pragma unroll
            for (int ni = 0; ni < 4; ++ni) {
                int row = ni * 16 + lr;
                f16x8 vf = *(const f16x8*)
                    &Vts[row * 64 + ((((ks << 2) | lg) ^ (row & 7)) << 3)];
                oacc[ni] = MFMA16(pf, vf, oacc[ni]);
            }
        }
        __syncthreads();
    }

    // normalize, store row-major [b*1024+s][h*64+d] f16
    size_t rbase = (size_t)b * Sseq + q0 + w * 16;
    #pragma unroll
    for (int r = 0; r < 4; ++r) {
        float inv = 1.0f / l_i[r];
        #pragma unroll
        for (int ni = 0; ni < 4; ++ni)
            o[(rbase + lg * 4 + r) * Dm + h * 64 + ni * 16 + lr] =
                (f16)(oacc[ni][r] * inv);
    }
}

// ---------------------------------------------------------------------------
// Buffer plan (ws = 32M f16 = 64MB, proven; d_out doubles as scratch):
//   ws f16 [0,3M):    wcatT (wq*QS | wk | wv, each [1024][1024])
//   ws f16 [3M,4M):   woT
//   ws f16 [4M,6M):   w1T   [2048][1024]
//   ws f16 [6M,8M):   w2T   [1024][2048]
//   ws f16 [8M,16M):  xn -> ob -> an
//   ws f16 [16M,32M): qh,kh -> h1
//   d_out out-half:   vh (8M f16) + vth (8M f16) -> final out (fp32)
//   d_out attn-half:  bcat fp32[3072] (dead at step 5) -> attn (output #2)
// ---------------------------------------------------------------------------
extern "C" void kernel_launch(void* const* d_in, const int* in_sizes, int n_in,
                              void* d_out, int out_size, void* d_ws, size_t ws_size,
                              hipStream_t stream)
{
    const float* x     = (const float*)d_in[0];
    const int*   mask  = (const int*)  d_in[1];
    const float* wq    = (const float*)d_in[2];
    const float* bq    = (const float*)d_in[3];
    const float* wk    = (const float*)d_in[4];
    const float* bk    = (const float*)d_in[5];
    const float* wv    = (const float*)d_in[6];
    const float* bv    = (const float*)d_in[7];
    const float* wo    = (const float*)d_in[8];
    const float* bo    = (const float*)d_in[9];
    const float* w1    = (const float*)d_in[10];
    const float* b1    = (const float*)d_in[11];
    const float* w2    = (const float*)d_in[12];
    const float* b2    = (const float*)d_in[13];
    const float* g1    = (const float*)d_in[14];
    const float* beta1 = (const float*)d_in[15];
    const float* g2    = (const float*)d_in[16];
    const float* beta2 = (const float*)d_in[17];

    float* out  = (float*)d_out;
    float* attn = out + EIGHT_M;

    const size_t M1 = 1024 * 1024;
    f16* ws16 = (f16*)d_ws;
    f16* wcatT = ws16;               // 3M
    f16* woT   = ws16 + 3 * M1;
    f16* w1T   = ws16 + 4 * M1;      // [2048][1024]
    f16* w2T   = ws16 + 6 * M1;      // [1024][2048]
    f16* xn    = ws16 + 8 * M1;      // 8M
    f16* ob    = xn;                 // alias (xn dead after QKV)
    f16* an    = xn;                 // alias (ob dead after O-proj)
    f16* qh    = ws16 + 16 * M1;     // 8M
    f16* kh    = ws16 + 24 * M1;     // 8M
    f16* h1    = qh;                 // 16M (q,k dead)
    f16* vh    = (f16*)d_out;        // out-half scratch
    f16* vth   = vh + 8 * M1;
    float* bcat = attn;              // 3072 fp32, dead before attn written

    dim3 tb256(256), tb512(512);

    // 0. weight prep
    transcast_k<<<dim3(32, 32), tb256, 0, stream>>>(wq, wcatT,          1024, 1024, QSCALE);
    transcast_k<<<dim3(32, 32), tb256, 0, stream>>>(wk, wcatT + 1 * M1, 1024, 1024, 1.0f);
    transcast_k<<<dim3(32, 32), tb256, 0, stream>>>(wv, wcatT + 2 * M1, 1024, 1024, 1.0f);
    transcast_k<<<dim3(32, 32), tb256, 0, stream>>>(wo, woT,            1024, 1024, 1.0f);
    transcast_k<<<dim3(64, 32), tb256, 0, stream>>>(w1, w1T,            1024, 2048, 1.0f);
    transcast_k<<<dim3(32, 64), tb256, 0, stream>>>(w2, w2T,            2048, 1024, 1.0f);
    biascat_k<<<12, tb256, 0, stream>>>(bq, bk, bv, bcat);

    // 1. LN1
    ln_k<<<ROWS, tb256, 0, stream>>>(x, g1, beta1, xn);

    // 2. fused QKV projection (head layout f16; Q pre-scaled by QSCALE)
    gemm2_k<0><<<dim3(3072 / 128, ROWS / 256), tb512, 0, stream>>>(
        xn, wcatT, bcat, qh, kh, vh, nullptr, ROWS, 3072, Dm);

    // 3. V -> V^T per head
    vtrans_k<<<dim3(16, 128), tb256, 0, stream>>>(vh, vth);

    // 4. flash attention -> ob row-major f16
    attn_k<<<dim3(16, 128), tb256, 0, stream>>>(qh, kh, vth, mask, ob);

    // 5. O projection + residual -> attn (fp32, output #2)
    gemm2_k<1><<<dim3(1024 / 128, ROWS / 256), tb512, 0, stream>>>(
        ob, woT, bo, attn, nullptr, nullptr, x, ROWS, Dm, Dm);

    // 6. LN2 -> an f16
    ln_k<<<ROWS, tb256, 0, stream>>>(attn, g2, beta2, an);

    // 7. FFN1: relu(an @ w1 + b1) -> h1 f16
    gemm2_k<2><<<dim3(2048 / 128, ROWS / 256), tb512, 0, stream>>>(
        an, w1T, b1, h1, nullptr, nullptr, nullptr, ROWS, DFF, Dm);

    // 8. FFN2: attn + h1 @ w2 + b2 -> out (fp32, output #1)
    gemm2_k<1><<<dim3(1024 / 128, ROWS / 256), tb512, 0, stream>>>(
        h1, w2T, b2, out, nullptr, nullptr, attn, ROWS, Dm, DFF);
}